// Round 18
// baseline (51.899 us; speedup 1.0000x reference)
//
#include <hip/hip_runtime.h>

#define N      4096
#define ON     4090
#define TILE_W 128
#define TILE_H 32
#define IN_H   38                 // 32 + 6 halo rows staged
#define LDS_W  136                // 134 used + pad (rows 16B-aligned)
#define BUFF   6144               // floats per buffer: 24 DMA chunks * 256
#define NTILE  4                  // tiles walked per block (128 rows)

__device__ __forceinline__ void gload_lds16(const float* g, float* l) {
    __builtin_amdgcn_global_load_lds(
        (const __attribute__((address_space(1))) void*)g,
        (__attribute__((address_space(3))) void*)l,
        16, 0, 0);   // 16 B/lane, dest = uniform base + lane*16
}

// Block-level 2-phase pipelined conv (T3-minimum):
//   per iter: issue 6 DMAs for tile t+1 -> counted vmcnt (never 0 mid-loop)
//   -> raw s_barrier -> compute tile t -> raw s_barrier.
// Next-tile loads stay in flight across the barrier (m201-proven pattern;
// raw __builtin_amdgcn_s_barrier does NOT force a vmcnt(0) drain).
__global__ __launch_bounds__(256, 3)
void conv7x7_pipe2(const float* __restrict__ x,
                   const float* __restrict__ w,
                   const float* __restrict__ bias,
                   float* __restrict__ out)
{
    __shared__ float lds[2 * BUFF];   // 49,152 B -> 3 blocks/CU

    const int tid  = threadIdx.x;
    const int lane = tid & 63;
    const int wv   = tid >> 6;

    const int x0  = blockIdx.x * TILE_W;        // x-fast grid: coherent writes
    const int yb  = blockIdx.y * (TILE_H * NTILE);
    const int xc0 = x0 >> 2;

    // per-wave stage of its 6 chunks (chunks wv*6 .. wv*6+5) of one window.
    // chunk m -> (row = m/34, cc = m%34); overshoot chunks (m >= 1292) write
    // the buffer pad region (floats 5168..6143), never read.
    auto stage = [&](float* buf, int y0t) {
        #pragma unroll
        for (int i = 0; i < 6; ++i) {
            const int k   = wv * 6 + i;
            const int m   = (k << 6) + lane;
            const int row = m / 34;                      // magic-mul
            const int cc  = m - row * 34;
            const int gy  = min(y0t + row, N - 1);       // edge clamps: junk
            const int gc  = min(xc0 + cc, (N >> 2) - 1); // feeds guarded outs
            gload_lds16(x + ((size_t)gy << 12) + ((size_t)gc << 2),
                        buf + (k << 8));
        }
    };

    // weights/bias: uniform addresses -> SGPRs
    float ws[49];
    #pragma unroll
    for (int i = 0; i < 49; ++i) ws[i] = w[i];
    const float bv = bias[0];

    stage(lds, yb);   // prologue: tile 0 -> buf0

    const int tau   = tid & 31;          // cols 4*tau .. 4*tau+3
    const int rg    = tid >> 5;          // rows 4*rg .. 4*rg+3
    const int colf  = tau << 2;
    const int rbase = rg << 2;
    const int ox    = x0 + colf;
    const bool inx  = (ox + 4 <= ON);

    #pragma unroll
    for (int t = 0; t < NTILE; ++t) {
        if (t + 1 < NTILE)
            stage(lds + (((t + 1) & 1) ? BUFF : 0), yb + (t + 1) * TILE_H);

        // counted wait for tile t's DMAs: allow everything newer to fly.
        // newer = [stores(t-1): 8] + [DMA(t+1): 6]
        if      (t == 0)         asm volatile("s_waitcnt vmcnt(6)"  ::: "memory");
        else if (t == NTILE - 1) asm volatile("s_waitcnt vmcnt(8)"  ::: "memory");
        else                     asm volatile("s_waitcnt vmcnt(14)" ::: "memory");
        __builtin_amdgcn_sched_barrier(0);   // no ds_read hoists above the wait
        __builtin_amdgcn_s_barrier();        // raw: in-flight loads survive

        const float* cbuf = lds + ((t & 1) ? BUFF : 0);
        const int y0t = yb + t * TILE_H;

        float acc[4][4] = {};
        #pragma unroll
        for (int rr = 0; rr < 10; ++rr) {    // 10 window rows -> 4 out rows
            const float* rp = cbuf + (rbase + rr) * LDS_W + colf;
            float v[10];
            const float4 a  = *reinterpret_cast<const float4*>(rp);
            const float4 bq = *reinterpret_cast<const float4*>(rp + 4);
            const float2 c  = *reinterpret_cast<const float2*>(rp + 8);
            v[0]=a.x;  v[1]=a.y;  v[2]=a.z;  v[3]=a.w;
            v[4]=bq.x; v[5]=bq.y; v[6]=bq.z; v[7]=bq.w;
            v[8]=c.x;  v[9]=c.y;

            #pragma unroll
            for (int r = 0; r < 4; ++r) {
                const int ky = rr - r;               // compile-time after unroll
                if (ky >= 0 && ky < 7) {
                    #pragma unroll
                    for (int kx = 0; kx < 7; ++kx) {
                        const float wk = ws[ky * 7 + kx];
                        #pragma unroll
                        for (int j = 0; j < 4; ++j)
                            acc[r][j] = fmaf(v[kx + j], wk, acc[r][j]);
                    }
                }
            }
        }

        const int oy0 = y0t + rbase;
        if (inx && oy0 + 4 <= ON) {
            #pragma unroll
            for (int r = 0; r < 4; ++r) {
                float* dst = out + (size_t)(oy0 + r) * ON + ox;   // 8B-aligned
                *reinterpret_cast<float2*>(dst)     = make_float2(acc[r][0] + bv, acc[r][1] + bv);
                *reinterpret_cast<float2*>(dst + 2) = make_float2(acc[r][2] + bv, acc[r][3] + bv);
            }
        } else {
            #pragma unroll
            for (int r = 0; r < 4; ++r) {
                const int oy = oy0 + r;
                if (oy < ON) {
                    float* dst = out + (size_t)oy * ON;
                    #pragma unroll
                    for (int j = 0; j < 4; ++j) {
                        const int oxj = ox + j;
                        if (oxj < ON) dst[oxj] = acc[r][j] + bv;
                    }
                }
            }
        }

        __builtin_amdgcn_s_barrier();   // all reads of buf[t] done before
    }                                   // buf[t] is restaged next iteration
}

extern "C" void kernel_launch(void* const* d_in, const int* in_sizes, int n_in,
                              void* d_out, int out_size, void* d_ws, size_t ws_size,
                              hipStream_t stream) {
    const float* x    = (const float*)d_in[0];
    const float* w    = (const float*)d_in[1];
    const float* bias = (const float*)d_in[2];
    float* out        = (float*)d_out;

    dim3 grid(32, 32);   // x-fast: consecutive blocks x-adjacent (clean writes)
    conv7x7_pipe2<<<grid, dim3(256, 1, 1), 0, stream>>>(x, w, bias, out);
}